// Round 4
// baseline (313.878 us; speedup 1.0000x reference)
//
#include <hip/hip_runtime.h>

// 3x3 valid conv (NCHW/OIHW) + bias + relu(y)*min(y+3,6)/6, fp32.
// x: (N=4096, C=3, 32, 32), w: (16, 3, 3, 3), out: (N, 16, 30, 30).
//
// Round 8 design (conv invariant ~140us across R4/R6/R7 despite pipe floors
// of <=45us => stall/serialization-bound, not pipe-bound):
//  - 4 images per block (grid 1024, 4 blocks/CU): amortize block start/stop,
//    prefetch next image's x into REGISTERS during current compute (T14
//    async-stage split) -> staging latency hidden for 3/4 images.
//  - Barrier-free epilogue: float4 j of chunk c is built from threads
//    4j..4j+3 = all in wave j/16, so the LDS transpose is WAVE-LOCAL.
//    sy[wave][16][64] wave-private; within-wave ds ordering replaces
//    __syncthreads. Barriers: ~9/image (R6) -> 2/image.
//  - Keep proven parts: SGPR weight path (s_load, v_fmac v,s,v), stride-1
//    conflict-free LDS x-reads, aligned float4 stores, acc[4][16] in the
//    <=128 VGPR band of __launch_bounds__(256,4) (R5 spill lesson).
//  - LDS 12KB sx + 16KB sy = 28KB -> 4 blocks/CU.

#define IMGS 4

__global__ __launch_bounds__(256, 4) void conv3x3_hswish(
    const float* __restrict__ x,
    const float* __restrict__ w,
    const float* __restrict__ bias,
    float* __restrict__ out)
{
    const int tid  = threadIdx.x;
    const int lane = tid & 63;
    const int wv   = tid >> 6;            // wave 0..3
    const int img0 = blockIdx.x * IMGS;

    __shared__ __align__(16) float sx[3072];   // image, 12 KB
    __shared__ __align__(16) float sy[4096];   // [wave][oc][64], 16 KB

    // Thread-constant pixel mapping: p = tid + k*256 (oh*30+ow), <900.
    int xb[4];
    #pragma unroll
    for (int k = 0; k < 4; ++k) {
        const int p = tid + k * 256;
        const int pc = p < 900 ? p : 899;   // dead slots clamp reads
        const int oh = pc / 30;
        xb[k] = oh * 32 + (pc - oh * 30);
    }

    // Bias via scalar path (uniform -> SGPR).
    float bb[16];
    #pragma unroll
    for (int oc = 0; oc < 16; ++oc) bb[oc] = bias[oc];

    // Prefetch image 0 into registers.
    float4 px0, px1, px2;
    {
        const float4* xg = (const float4*)(x + (size_t)img0 * 3072);
        px0 = xg[tid]; px1 = xg[tid + 256]; px2 = xg[tid + 512];
    }

    float4* s4 = (float4*)sx;

    #pragma unroll 1
    for (int im = 0; im < IMGS; ++im) {
        // Commit staged image to LDS (vmcnt wait here only stalls for im=0;
        // later images' loads completed under the previous compute).
        s4[tid] = px0; s4[tid + 256] = px1; s4[tid + 512] = px2;
        __syncthreads();

        // Issue next image's loads NOW; consumed only at next commit.
        if (im + 1 < IMGS) {
            const float4* xg =
                (const float4*)(x + (size_t)(img0 + im + 1) * 3072);
            px0 = xg[tid]; px1 = xg[tid + 256]; px2 = xg[tid + 512];
        }
        __builtin_amdgcn_sched_barrier(0);   // pin prefetch issue before loop

        float acc[4][16];
        #pragma unroll
        for (int k = 0; k < 4; ++k)
            #pragma unroll
            for (int oc = 0; oc < 16; ++oc) acc[k][oc] = 0.f;

        // Hot loop: dynamic ic, static (kh,kw); weights via s_load/SGPR.
        #pragma unroll 1
        for (int ic = 0; ic < 3; ++ic) {
            const float* __restrict__ wq = w + ic * 9;
            const int xbase = ic << 10;      // ic*1024
            #pragma unroll
            for (int kh = 0; kh < 3; ++kh) {
                #pragma unroll
                for (int kw = 0; kw < 3; ++kw) {
                    float ws[16];
                    #pragma unroll
                    for (int oc = 0; oc < 16; ++oc)
                        ws[oc] = wq[oc * 27 + kh * 3 + kw];
                    const int xoff = xbase + kh * 32 + kw;
                    #pragma unroll
                    for (int k = 0; k < 4; ++k) {
                        const float xv = sx[xoff + xb[k]];
                        #pragma unroll
                        for (int oc = 0; oc < 16; ++oc)
                            acc[k][oc] = fmaf(xv, ws[oc], acc[k][oc]);
                    }
                }
            }
        }

        // Wave-private transposed epilogue: NO barriers.
        // Wave w owns float4s j in [16w, 16w+16) of every (oc, chunk c).
        float* syw  = sy + (wv << 10);
        float* outn = out + (size_t)(img0 + im) * 14400;
        const int jj = lane & 15;
        const int j  = (wv << 4) + jj;
        #pragma unroll
        for (int c = 0; c < 4; ++c) {
            #pragma unroll
            for (int oc = 0; oc < 16; ++oc) {
                const float y = acc[c][oc] + bb[oc];
                // relu(y)*min(y+3,6)/6 == max(y,0)*min(y/6+0.5, 1)
                syw[oc * 64 + lane] =
                    fmaxf(y, 0.f) * fminf(fmaf(y, 1.f / 6.f, 0.5f), 1.f);
            }
            // Read back own wave's slots, store aligned float4.
            // Chunk 3 has 132 valid pixels = exactly 33 float4s.
            if (c < 3 || j < 33) {
                #pragma unroll
                for (int i = 0; i < 4; ++i) {
                    const int oc = (i << 2) + (lane >> 4);
                    const float4 v =
                        *(const float4*)(syw + oc * 64 + (jj << 2));
                    *(float4*)(outn + oc * 900 + c * 256 + (j << 2)) = v;
                }
            }
        }

        // All waves done reading sx before next commit overwrites it.
        __syncthreads();
    }
}

extern "C" void kernel_launch(void* const* d_in, const int* in_sizes, int n_in,
                              void* d_out, int out_size, void* d_ws, size_t ws_size,
                              hipStream_t stream) {
    const float* x    = (const float*)d_in[0];
    const float* w    = (const float*)d_in[1];
    const float* bias = (const float*)d_in[2];
    float* out        = (float*)d_out;

    const int N = in_sizes[0] / (3 * 32 * 32);  // 4096
    conv3x3_hswish<<<N / IMGS, 256, 0, stream>>>(x, w, bias, out);
}

// Round 5
// 298.178 us; speedup vs baseline: 1.0527x; 1.0527x over previous
//
#include <hip/hip_runtime.h>

// 3x3 valid conv (NCHW/OIHW) + bias + relu(y)*min(y+3,6)/6, fp32.
// x: (N=4096, C=3, 32, 32), w: (16, 3, 3, 3), out: (N, 16, 30, 30).
//
// Round 9 design:
//  - R8 post-mortem: round was machine-contaminated (fills 170us @5.5TB/s vs
//    147us @6.4TB/s other rounds); normalized, R8 was a mild win. Also R8's
//    prefetch was issued BEFORE __syncthreads -> drained by the barrier's
//    vmcnt(0), overlapping nothing. Fixed: prefetch after barrier.
//  - Main change: thread = horizontal 4-pixel group (slot g = oh*8 + ow/4,
//    240 slots). Per (ic,kh): ONE ds_read_b128 + ONE ds_read_b64 fetch the 6
//    columns serving all 3 kw x 4 px -> 18 LDS reads/img (was 108 b32), and
//    results store STRAIGHT from acc registers as aligned float2 pairs ->
//    sy staging (80 LDS ops) and ALL epilogue barriers gone.
//  - Double-buffered sx (2 x 3080 fl, pad covers the g=239 b64 overread) ->
//    no end-of-image barrier. Barriers: 9/img (R6) -> 1/img.
//  - Identical FMA order (ic->kh->kw) -> bitwise-identical output to R6/R8.
//  - Keep: SGPR weight path (16-value window, proven R5-R8), 4 img/block,
//    register prefetch, __launch_bounds__(256,4) (R5 spill lesson).

#define IMGS 4

__global__ __launch_bounds__(256, 4) void conv3x3_hswish(
    const float* __restrict__ x,
    const float* __restrict__ w,
    const float* __restrict__ bias,
    float* __restrict__ out)
{
    const int tid  = threadIdx.x;
    const int img0 = blockIdx.x * IMGS;

    // Double-buffered image; +8 pad so the tail group's b64 overread
    // (cols 32,33 past row end at ic=2,kh=2,g=239) stays in-allocation.
    __shared__ __align__(16) float sx[2][3080];

    // Slot: g = oh*8 + ow/4; threads 240..255 shadow slot 239, no store.
    const int g  = tid < 240 ? tid : 239;
    const int oh = g >> 3;
    const int ow = (g & 7) << 2;            // 0,4,...,28
    const int xrow0 = oh * 32 + ow;
    const bool active = tid < 240;
    const bool full   = ow < 28;            // ow=28 group has only 2 valid px

    // Bias via scalar path (uniform -> SGPR).
    float bb[16];
    #pragma unroll
    for (int oc = 0; oc < 16; ++oc) bb[oc] = bias[oc];

    // Prefetch image 0.
    float4 px0, px1, px2;
    {
        const float4* xg = (const float4*)(x + (size_t)img0 * 3072);
        px0 = xg[tid]; px1 = xg[tid + 256]; px2 = xg[tid + 512];
    }

    #pragma unroll 1
    for (int im = 0; im < IMGS; ++im) {
        float* buf = sx[im & 1];
        {   // Commit staged image (compiler inserts the vmcnt wait on px use).
            float4* s4 = (float4*)buf;
            s4[tid] = px0; s4[tid + 256] = px1; s4[tid + 512] = px2;
        }
        __syncthreads();

        // Issue next image's loads AFTER the barrier: they fly under the
        // whole compute phase, consumed at the next commit.
        if (im + 1 < IMGS) {
            const float4* xg =
                (const float4*)(x + (size_t)(img0 + im + 1) * 3072);
            px0 = xg[tid]; px1 = xg[tid + 256]; px2 = xg[tid + 512];
        }
        __builtin_amdgcn_sched_barrier(0);   // pin prefetch issue here

        float acc[4][16];
        #pragma unroll
        for (int k = 0; k < 4; ++k)
            #pragma unroll
            for (int oc = 0; oc < 16; ++oc) acc[k][oc] = 0.f;

        // Hot loop: dynamic ic, static (kh,kw); weights via s_load/SGPR.
        #pragma unroll 1
        for (int ic = 0; ic < 3; ++ic) {
            const float* __restrict__ wq = w + ic * 9;
            const float* xr = buf + (ic << 10) + xrow0;
            #pragma unroll
            for (int kh = 0; kh < 3; ++kh) {
                // 6 columns feed 3 kw x 4 px: one b128 + one b64.
                const float4 v4 = *(const float4*)(xr + kh * 32);
                const float2 v2 = *(const float2*)(xr + kh * 32 + 4);
                const float xv[6] = {v4.x, v4.y, v4.z, v4.w, v2.x, v2.y};
                #pragma unroll
                for (int kw = 0; kw < 3; ++kw) {
                    float ws[16];
                    #pragma unroll
                    for (int oc = 0; oc < 16; ++oc)
                        ws[oc] = wq[oc * 27 + kh * 3 + kw];   // uniform->SGPR
                    #pragma unroll
                    for (int k = 0; k < 4; ++k) {
                        const float xx = xv[k + kw];          // static index
                        #pragma unroll
                        for (int oc = 0; oc < 16; ++oc)
                            acc[k][oc] = fmaf(xx, ws[oc], acc[k][oc]);
                    }
                }
            }
        }

        // Epilogue: bias + hardswish*relu, direct float2 stores from regs.
        // 8B-aligned ((oh*30+ow) even); wave span per oc is contiguous.
        float* outb = out + (size_t)(img0 + im) * 14400 + oh * 30 + ow;
        if (active) {
            #pragma unroll
            for (int oc = 0; oc < 16; ++oc) {
                const float y0 = acc[0][oc] + bb[oc];
                const float y1 = acc[1][oc] + bb[oc];
                float2 r01;
                r01.x = fmaxf(y0, 0.f) * fminf(fmaf(y0, 1.f / 6.f, 0.5f), 1.f);
                r01.y = fmaxf(y1, 0.f) * fminf(fmaf(y1, 1.f / 6.f, 0.5f), 1.f);
                *(float2*)(outb + oc * 900) = r01;
                if (full) {
                    const float y2 = acc[2][oc] + bb[oc];
                    const float y3 = acc[3][oc] + bb[oc];
                    float2 r23;
                    r23.x = fmaxf(y2, 0.f) * fminf(fmaf(y2, 1.f / 6.f, 0.5f), 1.f);
                    r23.y = fmaxf(y3, 0.f) * fminf(fmaf(y3, 1.f / 6.f, 0.5f), 1.f);
                    *(float2*)(outb + oc * 900 + 2) = r23;
                }
            }
        }
        // No trailing barrier: next iteration writes the OTHER sx buffer.
    }
}

extern "C" void kernel_launch(void* const* d_in, const int* in_sizes, int n_in,
                              void* d_out, int out_size, void* d_ws, size_t ws_size,
                              hipStream_t stream) {
    const float* x    = (const float*)d_in[0];
    const float* w    = (const float*)d_in[1];
    const float* bias = (const float*)d_in[2];
    float* out        = (float*)d_out;

    const int N = in_sizes[0] / (3 * 32 * 32);  // 4096
    conv3x3_hswish<<<N / IMGS, 256, 0, stream>>>(x, w, bias, out);
}